// Round 1
// baseline (2543.907 us; speedup 1.0000x reference)
//
#include <hip/hip_runtime.h>
#include <hip/hip_fp16.h>

// ---------------------------------------------------------------------------
// EdgeClassifierGNN: 2x SAGEConv(mean)+BN+ReLU, then 3-layer edge MLP.
// Trick 1: lin_l before mean-aggregation (64-wide gather).
// Trick 2: edge-MLP layer 1 split: z1 = relu(u[src] + v[dst] + B1*attr).
// Trick 3: CSR by dst -> atomic-free aggregation; k_edge in dst order.
// Trick 4: node linears via register-blocked GEMM, BN fused on input.
// Trick 5: random-gather tables in fp16 (q 6.4 MB, u 12.8 MB).
// Trick 6: k_edge layer 2 via v_mfma_f32_16x16x32_f16 + shfl epilogue.
// Trick 7 (r9): k_agg wave-per-node with 8-edges-per-load gather + butterfly.
// Trick 8 (r10): k_edge processes edges in (dst>>12, src>>12) 2D-tiled order
//          so the U16 src-gather slice (1 MB) + V32 dst slice (2 MB) stay
//          L2-resident per XCD (kills the 205 MB zero-reuse gather traffic);
//          out written coalesced in processing order, then inverse-permuted
//          by a final gather pass (kills 44 MB partial-line write+RMW).
//          Permutation buffers alias dead P32/H1 -> no workspace growth.
// ---------------------------------------------------------------------------

#define EPS 1e-5f

typedef _Float16 h8 __attribute__((ext_vector_type(8)));
typedef float f32x4 __attribute__((ext_vector_type(4)));

// ---------------- CSR build + weight prep (merged) ----------------
__global__ __launch_bounds__(256) void k_prep_hist(
    const float* __restrict__ W1l, const float* __restrict__ W1r,
    const float* __restrict__ b1l,
    const float* __restrict__ W2l, const float* __restrict__ W2r,
    const float* __restrict__ b2l,
    const float* __restrict__ Wm1, const float* __restrict__ bm1,
    const float* __restrict__ Wm2,
    float* __restrict__ Wt1, float* __restrict__ Wt2, float* __restrict__ Wt3,
    float* __restrict__ bias1, float* __restrict__ bias2,
    float* __restrict__ bias3, float* __restrict__ BT,
    __half* __restrict__ W2B,
    const int* __restrict__ dst, int* __restrict__ deg, int E, int prepBlocks) {
  if ((int)blockIdx.x >= prepBlocks) {
    int e = (blockIdx.x - prepBlocks) * 256 + threadIdx.x;
    if (e < E) atomicAdd(&deg[dst[e]], 1);
    return;
  }
  int idx = blockIdx.x * 256 + threadIdx.x;
  if (idx < 16384) {  // Wt1 [128k x 128f] = [W1l | W1r]^T
    int k = idx >> 7, f = idx & 127;
    Wt1[idx] = (f < 64) ? W1l[f * 128 + k] : W1r[(f - 64) * 128 + k];
    return;
  }
  idx -= 16384;
  if (idx < 8192) {   // Wt2 [64k x 128f] = [W2l | W2r]^T
    int k = idx >> 7, f = idx & 127;
    Wt2[idx] = (f < 64) ? W2l[f * 64 + k] : W2r[(f - 64) * 64 + k];
    return;
  }
  idx -= 8192;
  if (idx < 16384) {  // Wt3 [64k x 256f] = [A1 | C1]^T  (col slices of Wm1)
    int k = idx >> 8, f = idx & 255;
    Wt3[idx] = (f < 128) ? Wm1[f * 144 + k] : Wm1[(f - 128) * 144 + 80 + k];
    return;
  }
  idx -= 16384;
  if (idx < 128) { bias1[idx] = (idx < 64) ? 0.f : b1l[idx - 64]; return; }
  idx -= 128;
  if (idx < 128) { bias2[idx] = (idx < 64) ? 0.f : b2l[idx - 64]; return; }
  idx -= 128;
  if (idx < 256) { bias3[idx] = (idx < 128) ? bm1[idx] : 0.f; return; }
  idx -= 256;
  if (idx < 2048) {   // BT [16k x 128c] = attr-slice of Wm1, fp32
    int k = idx >> 7, c = idx & 127;
    BT[idx] = Wm1[c * 144 + 64 + k];
    return;
  }
  idx -= 2048;
  if (idx < 8192) {   // W2B: Wm2^T pre-swizzled to MFMA B-fragment layout
    int j = idx & 7, l = (idx >> 3) & 63, f = idx >> 9;
    int kc = f >> 2, tt = f & 3;
    int col = 16 * tt + (l & 15);
    int k = 32 * kc + (l >> 4) * 8 + j;
    W2B[idx] = __float2half(Wm2[col * 128 + k]);
    return;
  }
}

__global__ __launch_bounds__(1024) void k_scan(
    const int* __restrict__ deg, int* __restrict__ rowptr,
    int* __restrict__ cursor, int N) {
  __shared__ int wsum[16];
  __shared__ int carry;
  const int lane = threadIdx.x & 63;
  const int w    = threadIdx.x >> 6;
  if (threadIdx.x == 0) carry = 0;
  __syncthreads();
  for (int base = 0; base < N; base += 1024) {
    int i = base + threadIdx.x;
    int v = (i < N) ? deg[i] : 0;
    int incl = v;
#pragma unroll
    for (int off = 1; off < 64; off <<= 1) {
      int t = __shfl_up(incl, off);
      if (lane >= off) incl += t;
    }
    if (lane == 63) wsum[w] = incl;
    __syncthreads();
    if (w == 0) {
      int ws_ = (lane < 16) ? wsum[lane] : 0;
      int wincl = ws_;
#pragma unroll
      for (int off = 1; off < 16; off <<= 1) {
        int t = __shfl_up(wincl, off);
        if (lane >= off) wincl += t;
      }
      if (lane < 16) wsum[lane] = wincl;
    }
    __syncthreads();
    int woff = carry + (w > 0 ? wsum[w - 1] : 0);
    int excl = woff + incl - v;
    if (i < N) { rowptr[i] = excl; cursor[i] = excl; }
    int tot = wsum[15];
    __syncthreads();
    if (threadIdx.x == 0) carry += tot;
    __syncthreads();
  }
  if (threadIdx.x == 0) rowptr[N] = carry;
}

// CSR scatter + 2D-bucket histogram (fused; bcnt pre-zeroed)
__global__ __launch_bounds__(256) void k_fill(
    const int* __restrict__ src, const int* __restrict__ dst,
    int* __restrict__ cursor, int* __restrict__ csr_src,
    int* __restrict__ csr_dst, int* __restrict__ csr_eid,
    int* __restrict__ bcnt, int E, int nseg) {
  int e = blockIdx.x * 256 + threadIdx.x;
  if (e < E) {
    int s = src[e];
    int d = dst[e];
    int pos = atomicAdd(&cursor[d], 1);
    csr_src[pos] = s;
    csr_dst[pos] = d;
    csr_eid[pos] = e;
    atomicAdd(&bcnt[(d >> 12) * nseg + (s >> 12)], 1);
  }
}

// exclusive scan of <=1024 bucket counts (single block, 256 threads x 4)
__global__ __launch_bounds__(256) void k_scan2(
    const int* __restrict__ cnt, int* __restrict__ cur, int nb) {
  __shared__ int wsum[4];
  const int t = threadIdx.x;
  const int lane = t & 63, w = t >> 6;
  const int base = t * 4;
  int v[4];
#pragma unroll
  for (int i = 0; i < 4; ++i) v[i] = (base + i < nb) ? cnt[base + i] : 0;
  int tot = v[0] + v[1] + v[2] + v[3];
  int incl = tot;
#pragma unroll
  for (int off = 1; off < 64; off <<= 1) {
    int x = __shfl_up(incl, off);
    if (lane >= off) incl += x;
  }
  if (lane == 63) wsum[w] = incl;
  __syncthreads();
  int woff = 0;
  for (int i = 0; i < w; ++i) woff += wsum[i];
  int excl = woff + incl - tot;
#pragma unroll
  for (int i = 0; i < 4; ++i) {
    if (base + i < nb) cur[base + i] = excl;
    excl += v[i];
  }
}

// stable partition of dst-sorted CSR edges into (dseg, sbucket) chunks;
// records inverse permutation pos[eid] = processing slot.
__global__ __launch_bounds__(256) void k_fill2(
    const int* __restrict__ csr_src, const int* __restrict__ csr_dst,
    const int* __restrict__ csr_eid, int* __restrict__ bcur,
    int* __restrict__ s2, int* __restrict__ d2, int* __restrict__ e2,
    int* __restrict__ pos, int E, int nseg) {
  int j = blockIdx.x * 256 + threadIdx.x;
  if (j < E) {
    int s = csr_src[j], d = csr_dst[j], eid = csr_eid[j];
    int p = atomicAdd(&bcur[(d >> 12) * nseg + (s >> 12)], 1);
    s2[p] = s;
    d2[p] = d;
    e2[p] = eid;
    pos[eid] = p;
  }
}

// final inverse-permute: coalesced write of out, gather from L2-resident out2
__global__ __launch_bounds__(256) void k_scatter_out(
    const float* __restrict__ out2, const int* __restrict__ pos,
    float* __restrict__ out, int E) {
  int e = blockIdx.x * 256 + threadIdx.x;
  if (e < E) {
    int p = pos[e];
    *(float2*)&out[(size_t)e * 2] = *(const float2*)&out2[(size_t)p * 2];
  }
}

// ---------------- register-blocked node GEMM ----------------
// MODE 0: cols 0-63 -> half outH (stride 64), 64-127 -> float outF (stride 64)
// MODE 3: blockIdx.y==0 -> half outH (stride 128); ==1 -> float outF, using
//         Wt+128/bias+128 (the V slice of the 256-wide concat).
template<int K, int MODE>
__global__ __launch_bounds__(256) void k_gemm(
    const float* __restrict__ X, const float* __restrict__ stats,
    const float* __restrict__ Wt, const float* __restrict__ bias,
    __half* __restrict__ outH, float* __restrict__ outF, int N, int Ftot) {
  __shared__ __align__(16) float Xs[32][68];
  __shared__ __align__(16) float Ws_[32][128];
  const int tid = threadIdx.x;
  const int tx  = tid & 15;
  const int ty  = tid >> 4;
  const int n0  = blockIdx.x * 64;
  int half2nd = 0;
  if constexpr (MODE == 3) half2nd = blockIdx.y;
  const float* WtB   = Wt + (half2nd ? 128 : 0);
  const float* biasB = bias + (half2nd ? 128 : 0);
  float acc[4][8];
#pragma unroll
  for (int j = 0; j < 8; ++j) {
    float bv = biasB[8 * tx + j];
#pragma unroll
    for (int i = 0; i < 4; ++i) acc[i][j] = bv;
  }
  for (int k0 = 0; k0 < K; k0 += 32) {
    __syncthreads();
#pragma unroll
    for (int l = 0; l < 2; ++l) {
      int idx = tid * 2 + l;
      int kq = idx & 7, n = idx >> 3;
      float4 xv = make_float4(0.f, 0.f, 0.f, 0.f);
      if (n0 + n < N) xv = *(const float4*)&X[(size_t)(n0 + n) * K + k0 + kq * 4];
      if (stats) {
        int kb = k0 + kq * 4;
        xv.x = fmaxf(xv.x * stats[128 + kb + 0] + stats[192 + kb + 0], 0.f);
        xv.y = fmaxf(xv.y * stats[128 + kb + 1] + stats[192 + kb + 1], 0.f);
        xv.z = fmaxf(xv.z * stats[128 + kb + 2] + stats[192 + kb + 2], 0.f);
        xv.w = fmaxf(xv.w * stats[128 + kb + 3] + stats[192 + kb + 3], 0.f);
      }
      Xs[kq * 4 + 0][n] = xv.x;
      Xs[kq * 4 + 1][n] = xv.y;
      Xs[kq * 4 + 2][n] = xv.z;
      Xs[kq * 4 + 3][n] = xv.w;
    }
#pragma unroll
    for (int l = 0; l < 4; ++l) {
      int idx = tid + l * 256;
      int kr = idx >> 5, fc = idx & 31;
      *(float4*)&Ws_[kr][fc * 4] =
          *(const float4*)&WtB[(size_t)(k0 + kr) * Ftot + fc * 4];
    }
    __syncthreads();
#pragma unroll
    for (int kk = 0; kk < 32; ++kk) {
      float4 a  = *(const float4*)&Xs[kk][4 * ty];
      float4 b0 = *(const float4*)&Ws_[kk][8 * tx];
      float4 b1 = *(const float4*)&Ws_[kk][8 * tx + 4];
      float aa[4] = {a.x, a.y, a.z, a.w};
      float bb[8] = {b0.x, b0.y, b0.z, b0.w, b1.x, b1.y, b1.z, b1.w};
#pragma unroll
      for (int i = 0; i < 4; ++i)
#pragma unroll
        for (int j = 0; j < 8; ++j) acc[i][j] += aa[i] * bb[j];
    }
  }
#pragma unroll
  for (int i = 0; i < 4; ++i) {
    int n = n0 + 4 * ty + i;
    if (n >= N) continue;
    if constexpr (MODE == 0) {
      if (tx < 8) {
        __half2 hh[4];
#pragma unroll
        for (int c = 0; c < 4; ++c)
          hh[c] = __floats2half2_rn(acc[i][2 * c], acc[i][2 * c + 1]);
        *(uint4*)&outH[(size_t)n * 64 + 8 * tx] = *(uint4*)hh;
      } else {
        float* cp = outF + (size_t)n * 64 + 8 * tx - 64;
        *(float4*)cp = make_float4(acc[i][0], acc[i][1], acc[i][2], acc[i][3]);
        *(float4*)(cp + 4) = make_float4(acc[i][4], acc[i][5], acc[i][6], acc[i][7]);
      }
    } else {  // MODE 3
      if (!half2nd) {
        __half2 hh[4];
#pragma unroll
        for (int c = 0; c < 4; ++c)
          hh[c] = __floats2half2_rn(acc[i][2 * c], acc[i][2 * c + 1]);
        *(uint4*)&outH[(size_t)n * 128 + 8 * tx] = *(uint4*)hh;
      } else {
        float* cp = outF + (size_t)n * 128 + 8 * tx;
        *(float4*)cp = make_float4(acc[i][0], acc[i][1], acc[i][2], acc[i][3]);
        *(float4*)(cp + 4) = make_float4(acc[i][4], acc[i][5], acc[i][6], acc[i][7]);
      }
    }
  }
}

// ---------------- fused aggregate + mean + residual + BN stats ----------------
// Wave-per-node. Lanes = 8 edge-groups (g=lane>>3) x 8 feature-octets (c=lane&7).
// One uint4 load per lane = 8 edges x 128 B per wave-instruction.
__global__ __launch_bounds__(256) void k_agg(
    const __half* __restrict__ qb, const float* __restrict__ pb,
    const int* __restrict__ rowptr, const int* __restrict__ csr_src,
    float* __restrict__ hpre, float* __restrict__ stats, int N) {
  __shared__ float red[512];
  const int tid  = threadIdx.x;
  const int w    = tid >> 6;
  const int lane = tid & 63;
  const int g    = lane >> 3, c = lane & 7;
  float lsum = 0.f, lsq = 0.f;
  const int wid = blockIdx.x * 4 + w;
  const int nw  = gridDim.x * 4;
  for (int n = wid; n < N; n += nw) {
    const int r0 = rowptr[n], r1 = rowptr[n + 1];
    float s[8] = {0.f, 0.f, 0.f, 0.f, 0.f, 0.f, 0.f, 0.f};
    for (int j = r0 + g; j < r1; j += 8) {
      int a = csr_src[j];
      uint4 rv = *(const uint4*)&qb[(size_t)a * 64 + 8 * c];
      const __half2* hp = (const __half2*)&rv;
#pragma unroll
      for (int q = 0; q < 4; ++q) {
        float2 f2 = __half22float2(hp[q]);
        s[2 * q]     += f2.x;
        s[2 * q + 1] += f2.y;
      }
    }
    // butterfly over the g bits (lane bits 3,4,5)
#pragma unroll
    for (int m = 8; m < 64; m <<= 1)
#pragma unroll
      for (int q = 0; q < 8; ++q) s[q] += __shfl_xor(s[q], m);
    // lane (g,c) finalizes feature f = 8c + g
    float sv = s[0];
#pragma unroll
    for (int q = 1; q < 8; ++q) sv = (g == q) ? s[q] : sv;
    float cdeg = (float)(r1 - r0);
    cdeg = cdeg > 1.f ? cdeg : 1.f;
    const int f = 8 * c + g;
    float v = sv / cdeg + pb[(size_t)n * 64 + f];
    hpre[(size_t)n * 64 + f] = v;
    lsum += v;
    lsq  += v * v;
  }
  red[tid]       = lsum;
  red[256 + tid] = lsq;
  __syncthreads();
  if (tid < 64) {  // same lane->feature map in every wave
    float ts = red[tid] + red[tid + 64] + red[tid + 128] + red[tid + 192];
    float tq = red[256 + tid] + red[256 + tid + 64] + red[256 + tid + 128] + red[256 + tid + 192];
    int f = 8 * (tid & 7) + (tid >> 3);
    atomicAdd(&stats[f], ts);
    atomicAdd(&stats[64 + f], tq);
  }
}

// stats -> BN scale/shift: sc=g*invstd, sh=be-mean*sc
__global__ void k_finalize(float* stats, const float* __restrict__ g,
                           const float* __restrict__ be, int N) {
  int f = threadIdx.x;  // 64 threads
  float inv_n = 1.0f / (float)N;
  float mean = stats[f] * inv_n;
  float var  = stats[64 + f] * inv_n - mean * mean;
  float s = g[f] * rsqrtf(var + EPS);
  stats[128 + f] = s;
  stats[192 + f] = be[f] - mean * s;
}

// ---------------------------------------------------------------------------
// Fused edge MLP over (dseg, sbucket)-tiled edge order, MFMA layer 2.
// Compute body identical to r9; only idx source + coalesced out2 write differ.
// ---------------------------------------------------------------------------
__global__ __launch_bounds__(256, 4) void k_edge(
    const __half* __restrict__ U16, const float* __restrict__ V32,
    const float* __restrict__ attr,
    const int* __restrict__ csrc, const int* __restrict__ cdst,
    const int* __restrict__ ceid,
    const __half* __restrict__ W2Bws, const float* __restrict__ BTws,
    const float* __restrict__ bm2, const float* __restrict__ Wm3,
    const float* __restrict__ bm3, float* __restrict__ out2, int E) {
  __shared__ __align__(16) _Float16 Z1f[64 * 136];
  __shared__ __align__(16) _Float16 W2B[8192];
  __shared__ __align__(16) float attrL[64 * 16];
  __shared__ int idxL[128];
  __shared__ int eidL[64];

  const int tid  = threadIdx.x;
  const int c4   = tid & 31;
  const int lane = tid & 63;
  const int w    = tid >> 6;
  const int ln15 = lane & 15;
  const int quad = lane >> 4;

  for (int i = tid; i < 1024; i += 256)
    ((uint4*)W2B)[i] = ((const uint4*)W2Bws)[i];

  float bmv[4], w30[4], w31[4];
#pragma unroll
  for (int t = 0; t < 4; ++t) {
    bmv[t] = bm2[16 * t + ln15];
    w30[t] = Wm3[16 * t + ln15];
    w31[t] = Wm3[64 + 16 * t + ln15];
  }
  const float bm30 = bm3[0], bm31 = bm3[1];

  const __half2* uh2 = (const __half2*)U16;
  const float4*  v4  = (const float4*)V32;
  const float4*  at4 = (const float4*)attr;
  const float4*  bt4 = (const float4*)BTws;

  const int nt = (E + 63) >> 6;
  for (int t = blockIdx.x; t < nt; t += gridDim.x) {
    const int e0 = t << 6;
    __syncthreads();

    if (tid < 64) {
      int j = e0 + tid;
      idxL[tid]      = (j < E) ? csrc[j] : 0;
      idxL[64 + tid] = (j < E) ? cdst[j] : 0;
      eidL[tid]      = (j < E) ? ceid[j] : -1;
    }
    float4 breg[16];
#pragma unroll
    for (int k = 0; k < 16; ++k) breg[k] = bt4[k * 32 + c4];
    __syncthreads();

    {
      int e = tid >> 2, k4 = tid & 3;
      int eid = eidL[e];
      float4 av = make_float4(0.f, 0.f, 0.f, 0.f);
      if (eid >= 0) av = at4[(size_t)eid * 4 + k4];
      ((float4*)attrL)[tid] = av;
    }
    __syncthreads();

#pragma unroll
    for (int it = 0; it < 8; ++it) {
      const int e = it * 8 + (tid >> 5);
      uint2 ur = *(const uint2*)&uh2[(size_t)idxL[e] * 64 + 2 * c4];
      float2 u01 = __half22float2(*reinterpret_cast<__half2*>(&ur.x));
      float2 u23 = __half22float2(*reinterpret_cast<__half2*>(&ur.y));
      float4 b = v4[(size_t)idxL[64 + e] * 32 + c4];
      float sx = u01.x + b.x, sy = u01.y + b.y;
      float sz = u23.x + b.z, sw = u23.y + b.w;
#pragma unroll
      for (int k = 0; k < 16; ++k) {
        float av = attrL[e * 16 + k];
        sx += av * breg[k].x; sy += av * breg[k].y;
        sz += av * breg[k].z; sw += av * breg[k].w;
      }
      __half2* zp = (__half2*)&Z1f[e * 136 + 4 * c4];
      zp[0] = __floats2half2_rn(fmaxf(sx, 0.f), fmaxf(sy, 0.f));
      zp[1] = __floats2half2_rn(fmaxf(sz, 0.f), fmaxf(sw, 0.f));
    }
    __syncthreads();

    f32x4 acc[4];
#pragma unroll
    for (int tt = 0; tt < 4; ++tt)
      acc[tt] = (f32x4){bmv[tt], bmv[tt], bmv[tt], bmv[tt]};
#pragma unroll
    for (int kc = 0; kc < 4; ++kc) {
      h8 a = *(const h8*)&Z1f[(16 * w + ln15) * 136 + 32 * kc + 8 * quad];
#pragma unroll
      for (int tt = 0; tt < 4; ++tt) {
        h8 bf = *(const h8*)&W2B[((kc * 4 + tt) * 64 + lane) * 8];
        acc[tt] = __builtin_amdgcn_mfma_f32_16x16x32_f16(a, bf, acc[tt], 0, 0, 0);
      }
    }

    float p0[4], p1[4];
#pragma unroll
    for (int r = 0; r < 4; ++r) { p0[r] = 0.f; p1[r] = 0.f; }
#pragma unroll
    for (int tt = 0; tt < 4; ++tt)
#pragma unroll
      for (int r = 0; r < 4; ++r) {
        float z = fmaxf(acc[tt][r], 0.f);
        p0[r] += z * w30[tt];
        p1[r] += z * w31[tt];
      }
#pragma unroll
    for (int r = 0; r < 4; ++r) {
#pragma unroll
      for (int m = 1; m < 16; m <<= 1) {
        p0[r] += __shfl_xor(p0[r], m);
        p1[r] += __shfl_xor(p1[r], m);
      }
      if (ln15 == 0) {
        int e = 16 * w + 4 * quad + r;
        int j = e0 + e;
        if (j < E)
          *(float2*)&out2[(size_t)j * 2] = make_float2(p0[r] + bm30, p1[r] + bm31);
      }
    }
  }
}

extern "C" void kernel_launch(void* const* d_in, const int* in_sizes, int n_in,
                              void* d_out, int out_size, void* d_ws, size_t ws_size,
                              hipStream_t stream) {
  const float* x    = (const float*)d_in[0];
  const int*   ei   = (const int*)d_in[1];
  const float* attr = (const float*)d_in[2];
  const float* W1l  = (const float*)d_in[3];
  const float* b1l  = (const float*)d_in[4];
  const float* W1r  = (const float*)d_in[5];
  const float* g1   = (const float*)d_in[6];
  const float* be1  = (const float*)d_in[7];
  const float* W2l  = (const float*)d_in[8];
  const float* b2l  = (const float*)d_in[9];
  const float* W2r  = (const float*)d_in[10];
  const float* g2   = (const float*)d_in[11];
  const float* be2  = (const float*)d_in[12];
  const float* Wm1  = (const float*)d_in[13];
  const float* bm1  = (const float*)d_in[14];
  const float* Wm2  = (const float*)d_in[15];
  const float* bm2  = (const float*)d_in[16];
  const float* Wm3  = (const float*)d_in[17];
  const float* bm3  = (const float*)d_in[18];
  float* out = (float*)d_out;

  const int N = in_sizes[0] / 128;
  const int E = in_sizes[1] / 2;
  const int* srcI = ei;
  const int* dstI = ei + E;

  float* ws = (float*)d_ws;
  const size_t NF = (size_t)N * 64;
  float*  P32 = ws;                        // [N][64] f32
  float*  H1  = ws + NF;                   // [N][64] f32 (reused as H2)
  float*  V32 = ws + 2 * NF;               // [N][128] f32
  __half* Q16 = (__half*)(ws + 4 * NF);    // [N][64] f16
  __half* U16 = (__half*)(ws + 4 * NF + NF / 2);  // [N][128] f16
  float* small  = ws + 5 * NF + NF / 2;
  float* stats1 = small;          // 256
  float* stats2 = stats1 + 256;   // 256
  float* Wt1    = stats2 + 256;   // 128*128
  float* Wt2    = Wt1 + 16384;    // 64*128
  float* Wt3    = Wt2 + 8192;     // 64*256
  float* bias1  = Wt3 + 16384;    // 128
  float* bias2  = bias1 + 128;    // 128
  float* bias3  = bias2 + 128;    // 256
  float* BTws   = bias3 + 256;    // 16*128
  __half* W2B   = (__half*)(BTws + 2048);   // 8192 halfs = 4096 floats
  int* rowptr = (int*)(BTws + 2048 + 4096); // N+1
  int* cursor = rowptr + (N + 1);           // N
  int* deg    = cursor + N;                 // N
  int* csrsrc = deg + N;                    // E
  int* csrdst = csrsrc + E;                 // E
  int* csreid = csrdst + E;                 // E
  int* bcnt   = csreid + E;                 // <=1024 bucket counters

  // 2D-tiled edge-order buffers alias dead regions (used only after k_gemm<64,3>):
  int* s2  = (int*)P32;         // E  (P32 dead after 2nd k_agg)
  int* d2  = s2 + E;            // E
  int* e2  = d2 + E;            // E
  int* pos = e2 + E;            // E   (4E ints == NF floats exactly for deg 16)
  float* out2 = H1;             // 2E floats (H1 dead after k_gemm<64,3>)
  int* bcur = cursor;           // cursor dead after k_fill

  const int nseg = (N + 4095) >> 12;   // 4096-node segments (13 for N=50000)
  const int nb   = nseg * nseg;        // 169 buckets

  hipMemsetAsync(deg, 0, (size_t)N * sizeof(int), stream);
  hipMemsetAsync(stats1, 0, 512 * sizeof(float), stream);
  hipMemsetAsync(bcnt, 0, (size_t)nb * sizeof(int), stream);

  // ---- weight prep + degree histogram (one launch) ----
  const int eBlocks = (E + 255) / 256;
  const int prepBlocks = (51712 + 255) / 256;
  k_prep_hist<<<prepBlocks + eBlocks, 256, 0, stream>>>(
      W1l, W1r, b1l, W2l, W2r, b2l, Wm1, bm1, Wm2,
      Wt1, Wt2, Wt3, bias1, bias2, bias3, BTws, W2B,
      dstI, deg, E, prepBlocks);
  k_scan<<<1, 1024, 0, stream>>>(deg, rowptr, cursor, N);
  k_fill<<<eBlocks, 256, 0, stream>>>(srcI, dstI, cursor, csrsrc, csrdst,
                                      csreid, bcnt, E, nseg);

  const int mTiles = (N + 63) / 64;

  // ---- conv1: Q16 = fp16(x@W1l^T), P32 = x@W1r^T + b1l ----
  k_gemm<128, 0><<<mTiles, 256, 0, stream>>>(x, nullptr, Wt1, bias1, Q16, P32, N, 128);
  k_agg<<<1024, 256, 0, stream>>>(Q16, P32, rowptr, csrsrc, H1, stats1, N);
  k_finalize<<<1, 64, 0, stream>>>(stats1, g1, be1, N);

  // ---- conv2 (BN1+relu fused into GEMM input) ----
  k_gemm<64, 0><<<mTiles, 256, 0, stream>>>(H1, stats1, Wt2, bias2, Q16, P32, N, 128);
  k_agg<<<1024, 256, 0, stream>>>(Q16, P32, rowptr, csrsrc, H1, stats2, N);  // H2=H1
  k_finalize<<<1, 64, 0, stream>>>(stats2, g2, be2, N);

  // ---- U16 / V32 in one launch (BN2+relu fused) ----
  k_gemm<64, 3><<<dim3(mTiles, 2), 256, 0, stream>>>(H1, stats2, Wt3, bias3,
                                                     U16, V32, N, 256);

  // ---- build 2D-tiled edge order (P32/H1 now dead -> buffers valid) ----
  k_scan2<<<1, 256, 0, stream>>>(bcnt, bcur, nb);
  k_fill2<<<eBlocks, 256, 0, stream>>>(csrsrc, csrdst, csreid, bcur,
                                       s2, d2, e2, pos, E, nseg);

  // ---- fused edge MLP over tiled edges (MFMA layer 2), coalesced out2 ----
  k_edge<<<1024, 256, 0, stream>>>(U16, V32, attr, s2, d2, e2,
                                   W2B, BTws, bm2, Wm3, bm3, out2, E);
  // ---- inverse-permute to final output order ----
  k_scatter_out<<<eBlocks, 256, 0, stream>>>(out2, pos, out, E);
}

// Round 2
// 703.027 us; speedup vs baseline: 3.6185x; 3.6185x over previous
//
#include <hip/hip_runtime.h>
#include <hip/hip_fp16.h>

// ---------------------------------------------------------------------------
// EdgeClassifierGNN: 2x SAGEConv(mean)+BN+ReLU, then 3-layer edge MLP.
// Trick 1: lin_l before mean-aggregation (64-wide gather).
// Trick 2: edge-MLP layer 1 split: z1 = relu(u[src] + v[dst] + B1*attr).
// Trick 3: CSR by dst -> atomic-free aggregation; k_edge in dst order.
// Trick 4: node linears via register-blocked GEMM, BN fused on input.
// Trick 5: random-gather tables in fp16 (q 6.4 MB, u 12.8 MB).
// Trick 6: k_edge layer 2 via v_mfma_f32_16x16x32_f16 + shfl epilogue.
// Trick 7 (r9): k_agg wave-per-node with 8-edges-per-load gather + butterfly.
// Trick 8 (r10): k_edge processes edges in (dst>>12, src>>12) 2D-tiled order
//          so the U16 src-gather slice (1 MB) + V32 dst slice (2 MB) stay
//          L2-resident per XCD; out written coalesced in processing order,
//          then inverse-permuted by a final gather pass.
// Trick 9 (r11): the 2D-tiled permutation built via contention-free counting
//          sort: per-chunk LDS histograms -> one-block scan -> LDS-cursor
//          scatter. (r10's 800k global atomics on 169 counters serialized at
//          ~1.5 ms; LDS atomics + coalesced histogram writes remove that.)
// ---------------------------------------------------------------------------

#define EPS 1e-5f
#define NBLK 256   // chunks for the counting sort

typedef _Float16 h8 __attribute__((ext_vector_type(8)));
typedef float f32x4 __attribute__((ext_vector_type(4)));

// ---------------- CSR build + weight prep (merged) ----------------
__global__ __launch_bounds__(256) void k_prep_hist(
    const float* __restrict__ W1l, const float* __restrict__ W1r,
    const float* __restrict__ b1l,
    const float* __restrict__ W2l, const float* __restrict__ W2r,
    const float* __restrict__ b2l,
    const float* __restrict__ Wm1, const float* __restrict__ bm1,
    const float* __restrict__ Wm2,
    float* __restrict__ Wt1, float* __restrict__ Wt2, float* __restrict__ Wt3,
    float* __restrict__ bias1, float* __restrict__ bias2,
    float* __restrict__ bias3, float* __restrict__ BT,
    __half* __restrict__ W2B,
    const int* __restrict__ dst, int* __restrict__ deg, int E, int prepBlocks) {
  if ((int)blockIdx.x >= prepBlocks) {
    int e = (blockIdx.x - prepBlocks) * 256 + threadIdx.x;
    if (e < E) atomicAdd(&deg[dst[e]], 1);
    return;
  }
  int idx = blockIdx.x * 256 + threadIdx.x;
  if (idx < 16384) {  // Wt1 [128k x 128f] = [W1l | W1r]^T
    int k = idx >> 7, f = idx & 127;
    Wt1[idx] = (f < 64) ? W1l[f * 128 + k] : W1r[(f - 64) * 128 + k];
    return;
  }
  idx -= 16384;
  if (idx < 8192) {   // Wt2 [64k x 128f] = [W2l | W2r]^T
    int k = idx >> 7, f = idx & 127;
    Wt2[idx] = (f < 64) ? W2l[f * 64 + k] : W2r[(f - 64) * 64 + k];
    return;
  }
  idx -= 8192;
  if (idx < 16384) {  // Wt3 [64k x 256f] = [A1 | C1]^T  (col slices of Wm1)
    int k = idx >> 8, f = idx & 255;
    Wt3[idx] = (f < 128) ? Wm1[f * 144 + k] : Wm1[(f - 128) * 144 + 80 + k];
    return;
  }
  idx -= 16384;
  if (idx < 128) { bias1[idx] = (idx < 64) ? 0.f : b1l[idx - 64]; return; }
  idx -= 128;
  if (idx < 128) { bias2[idx] = (idx < 64) ? 0.f : b2l[idx - 64]; return; }
  idx -= 128;
  if (idx < 256) { bias3[idx] = (idx < 128) ? bm1[idx] : 0.f; return; }
  idx -= 256;
  if (idx < 2048) {   // BT [16k x 128c] = attr-slice of Wm1, fp32
    int k = idx >> 7, c = idx & 127;
    BT[idx] = Wm1[c * 144 + 64 + k];
    return;
  }
  idx -= 2048;
  if (idx < 8192) {   // W2B: Wm2^T pre-swizzled to MFMA B-fragment layout
    int j = idx & 7, l = (idx >> 3) & 63, f = idx >> 9;
    int kc = f >> 2, tt = f & 3;
    int col = 16 * tt + (l & 15);
    int k = 32 * kc + (l >> 4) * 8 + j;
    W2B[idx] = __float2half(Wm2[col * 128 + k]);
    return;
  }
}

__global__ __launch_bounds__(1024) void k_scan(
    const int* __restrict__ deg, int* __restrict__ rowptr,
    int* __restrict__ cursor, int N) {
  __shared__ int wsum[16];
  __shared__ int carry;
  const int lane = threadIdx.x & 63;
  const int w    = threadIdx.x >> 6;
  if (threadIdx.x == 0) carry = 0;
  __syncthreads();
  for (int base = 0; base < N; base += 1024) {
    int i = base + threadIdx.x;
    int v = (i < N) ? deg[i] : 0;
    int incl = v;
#pragma unroll
    for (int off = 1; off < 64; off <<= 1) {
      int t = __shfl_up(incl, off);
      if (lane >= off) incl += t;
    }
    if (lane == 63) wsum[w] = incl;
    __syncthreads();
    if (w == 0) {
      int ws_ = (lane < 16) ? wsum[lane] : 0;
      int wincl = ws_;
#pragma unroll
      for (int off = 1; off < 16; off <<= 1) {
        int t = __shfl_up(wincl, off);
        if (lane >= off) wincl += t;
      }
      if (lane < 16) wsum[lane] = wincl;
    }
    __syncthreads();
    int woff = carry + (w > 0 ? wsum[w - 1] : 0);
    int excl = woff + incl - v;
    if (i < N) { rowptr[i] = excl; cursor[i] = excl; }
    int tot = wsum[15];
    __syncthreads();
    if (threadIdx.x == 0) carry += tot;
    __syncthreads();
  }
  if (threadIdx.x == 0) rowptr[N] = carry;
}

__global__ __launch_bounds__(256) void k_fill(
    const int* __restrict__ src, const int* __restrict__ dst,
    int* __restrict__ cursor, int* __restrict__ csr_src,
    int* __restrict__ csr_dst, int* __restrict__ csr_eid, int E) {
  int e = blockIdx.x * 256 + threadIdx.x;
  if (e < E) {
    int d = dst[e];
    int pos = atomicAdd(&cursor[d], 1);
    csr_src[pos] = src[e];
    csr_dst[pos] = d;
    csr_eid[pos] = e;
  }
}

// ---- counting sort of CSR edges into (dseg, sbucket) order, contention-free.
// Each of NBLK blocks owns a contiguous CSR chunk; dst-sorted input means a
// chunk touches only ~2*nseg distinct buckets -> LDS histogram is cheap.
__global__ __launch_bounds__(256) void k_hist(
    const int* __restrict__ csr_src, const int* __restrict__ csr_dst,
    int* __restrict__ hist, int E, int nseg, int nb, int chunk) {
  __shared__ int h[1024];
  const int tid = threadIdx.x;
  for (int i = tid; i < nb; i += 256) h[i] = 0;
  __syncthreads();
  const int j0 = blockIdx.x * chunk;
  const int j1 = min(E, j0 + chunk);
  for (int j = j0 + tid; j < j1; j += 256) {
    int key = (csr_dst[j] >> 12) * nseg + (csr_src[j] >> 12);
    atomicAdd(&h[key], 1);
  }
  __syncthreads();
  for (int i = tid; i < nb; i += 256) hist[blockIdx.x * nb + i] = h[i];
}

// single block: poff[blk][b] = exclusive prefix of hist over blk (per bucket);
// base[b] = exclusive prefix of bucket totals.
__global__ __launch_bounds__(1024) void k_scan2b(
    const int* __restrict__ hist, int* __restrict__ poff,
    int* __restrict__ base, int nb) {
  __shared__ int tot[1024];
  const int tid = threadIdx.x;
  const int lane = tid & 63, w = tid >> 6;  // 16 waves
  for (int b = w; b < nb; b += 16) {
    int v[4];
    int s = 0;
#pragma unroll
    for (int i = 0; i < 4; ++i) {
      v[i] = hist[(size_t)(lane * 4 + i) * nb + b];
      s += v[i];
    }
    int incl = s;
#pragma unroll
    for (int off = 1; off < 64; off <<= 1) {
      int t = __shfl_up(incl, off);
      if (lane >= off) incl += t;
    }
    int excl = incl - s;
#pragma unroll
    for (int i = 0; i < 4; ++i) {
      poff[(size_t)(lane * 4 + i) * nb + b] = excl;
      excl += v[i];
    }
    if (lane == 63) tot[b] = incl;
  }
  __syncthreads();
  if (w == 0) {
    const int per = (nb + 63) >> 6;  // <=4 for nb<=256
    int v[4];
    int s = 0;
#pragma unroll
    for (int i = 0; i < 4; ++i) {
      int idx = lane * per + i;
      v[i] = (i < per && idx < nb) ? tot[idx] : 0;
      s += v[i];
    }
    int incl = s;
#pragma unroll
    for (int off = 1; off < 64; off <<= 1) {
      int t = __shfl_up(incl, off);
      if (lane >= off) incl += t;
    }
    int excl = incl - s;
#pragma unroll
    for (int i = 0; i < 4; ++i) {
      int idx = lane * per + i;
      if (i < per && idx < nb) base[idx] = excl;
      excl += v[i];
    }
  }
}

// scatter into tiled order using LDS cursors (no global atomics);
// records inverse permutation pos[eid] = processing slot.
__global__ __launch_bounds__(256) void k_fill2b(
    const int* __restrict__ csr_src, const int* __restrict__ csr_dst,
    const int* __restrict__ csr_eid,
    const int* __restrict__ poff, const int* __restrict__ base,
    int* __restrict__ s2, int* __restrict__ d2, int* __restrict__ e2,
    int* __restrict__ pos, int E, int nseg, int nb, int chunk) {
  __shared__ int cur[1024];
  const int tid = threadIdx.x;
  for (int i = tid; i < nb; i += 256)
    cur[i] = base[i] + poff[(size_t)blockIdx.x * nb + i];
  __syncthreads();
  const int j0 = blockIdx.x * chunk;
  const int j1 = min(E, j0 + chunk);
  for (int j = j0 + tid; j < j1; j += 256) {
    int s = csr_src[j], d = csr_dst[j], eid = csr_eid[j];
    int key = (d >> 12) * nseg + (s >> 12);
    int p = atomicAdd(&cur[key], 1);
    s2[p] = s;
    d2[p] = d;
    e2[p] = eid;
    pos[eid] = p;
  }
}

// final inverse-permute: coalesced write of out, gather from L2-resident out2
__global__ __launch_bounds__(256) void k_scatter_out(
    const float* __restrict__ out2, const int* __restrict__ pos,
    float* __restrict__ out, int E) {
  int e = blockIdx.x * 256 + threadIdx.x;
  if (e < E) {
    int p = pos[e];
    *(float2*)&out[(size_t)e * 2] = *(const float2*)&out2[(size_t)p * 2];
  }
}

// ---------------- register-blocked node GEMM ----------------
// MODE 0: cols 0-63 -> half outH (stride 64), 64-127 -> float outF (stride 64)
// MODE 3: blockIdx.y==0 -> half outH (stride 128); ==1 -> float outF, using
//         Wt+128/bias+128 (the V slice of the 256-wide concat).
template<int K, int MODE>
__global__ __launch_bounds__(256) void k_gemm(
    const float* __restrict__ X, const float* __restrict__ stats,
    const float* __restrict__ Wt, const float* __restrict__ bias,
    __half* __restrict__ outH, float* __restrict__ outF, int N, int Ftot) {
  __shared__ __align__(16) float Xs[32][68];
  __shared__ __align__(16) float Ws_[32][128];
  const int tid = threadIdx.x;
  const int tx  = tid & 15;
  const int ty  = tid >> 4;
  const int n0  = blockIdx.x * 64;
  int half2nd = 0;
  if constexpr (MODE == 3) half2nd = blockIdx.y;
  const float* WtB   = Wt + (half2nd ? 128 : 0);
  const float* biasB = bias + (half2nd ? 128 : 0);
  float acc[4][8];
#pragma unroll
  for (int j = 0; j < 8; ++j) {
    float bv = biasB[8 * tx + j];
#pragma unroll
    for (int i = 0; i < 4; ++i) acc[i][j] = bv;
  }
  for (int k0 = 0; k0 < K; k0 += 32) {
    __syncthreads();
#pragma unroll
    for (int l = 0; l < 2; ++l) {
      int idx = tid * 2 + l;
      int kq = idx & 7, n = idx >> 3;
      float4 xv = make_float4(0.f, 0.f, 0.f, 0.f);
      if (n0 + n < N) xv = *(const float4*)&X[(size_t)(n0 + n) * K + k0 + kq * 4];
      if (stats) {
        int kb = k0 + kq * 4;
        xv.x = fmaxf(xv.x * stats[128 + kb + 0] + stats[192 + kb + 0], 0.f);
        xv.y = fmaxf(xv.y * stats[128 + kb + 1] + stats[192 + kb + 1], 0.f);
        xv.z = fmaxf(xv.z * stats[128 + kb + 2] + stats[192 + kb + 2], 0.f);
        xv.w = fmaxf(xv.w * stats[128 + kb + 3] + stats[192 + kb + 3], 0.f);
      }
      Xs[kq * 4 + 0][n] = xv.x;
      Xs[kq * 4 + 1][n] = xv.y;
      Xs[kq * 4 + 2][n] = xv.z;
      Xs[kq * 4 + 3][n] = xv.w;
    }
#pragma unroll
    for (int l = 0; l < 4; ++l) {
      int idx = tid + l * 256;
      int kr = idx >> 5, fc = idx & 31;
      *(float4*)&Ws_[kr][fc * 4] =
          *(const float4*)&WtB[(size_t)(k0 + kr) * Ftot + fc * 4];
    }
    __syncthreads();
#pragma unroll
    for (int kk = 0; kk < 32; ++kk) {
      float4 a  = *(const float4*)&Xs[kk][4 * ty];
      float4 b0 = *(const float4*)&Ws_[kk][8 * tx];
      float4 b1 = *(const float4*)&Ws_[kk][8 * tx + 4];
      float aa[4] = {a.x, a.y, a.z, a.w};
      float bb[8] = {b0.x, b0.y, b0.z, b0.w, b1.x, b1.y, b1.z, b1.w};
#pragma unroll
      for (int i = 0; i < 4; ++i)
#pragma unroll
        for (int j = 0; j < 8; ++j) acc[i][j] += aa[i] * bb[j];
    }
  }
#pragma unroll
  for (int i = 0; i < 4; ++i) {
    int n = n0 + 4 * ty + i;
    if (n >= N) continue;
    if constexpr (MODE == 0) {
      if (tx < 8) {
        __half2 hh[4];
#pragma unroll
        for (int c = 0; c < 4; ++c)
          hh[c] = __floats2half2_rn(acc[i][2 * c], acc[i][2 * c + 1]);
        *(uint4*)&outH[(size_t)n * 64 + 8 * tx] = *(uint4*)hh;
      } else {
        float* cp = outF + (size_t)n * 64 + 8 * tx - 64;
        *(float4*)cp = make_float4(acc[i][0], acc[i][1], acc[i][2], acc[i][3]);
        *(float4*)(cp + 4) = make_float4(acc[i][4], acc[i][5], acc[i][6], acc[i][7]);
      }
    } else {  // MODE 3
      if (!half2nd) {
        __half2 hh[4];
#pragma unroll
        for (int c = 0; c < 4; ++c)
          hh[c] = __floats2half2_rn(acc[i][2 * c], acc[i][2 * c + 1]);
        *(uint4*)&outH[(size_t)n * 128 + 8 * tx] = *(uint4*)hh;
      } else {
        float* cp = outF + (size_t)n * 128 + 8 * tx;
        *(float4*)cp = make_float4(acc[i][0], acc[i][1], acc[i][2], acc[i][3]);
        *(float4*)(cp + 4) = make_float4(acc[i][4], acc[i][5], acc[i][6], acc[i][7]);
      }
    }
  }
}

// ---------------- fused aggregate + mean + residual + BN stats ----------------
// Wave-per-node. Lanes = 8 edge-groups (g=lane>>3) x 8 feature-octets (c=lane&7).
// One uint4 load per lane = 8 edges x 128 B per wave-instruction.
__global__ __launch_bounds__(256) void k_agg(
    const __half* __restrict__ qb, const float* __restrict__ pb,
    const int* __restrict__ rowptr, const int* __restrict__ csr_src,
    float* __restrict__ hpre, float* __restrict__ stats, int N) {
  __shared__ float red[512];
  const int tid  = threadIdx.x;
  const int w    = tid >> 6;
  const int lane = tid & 63;
  const int g    = lane >> 3, c = lane & 7;
  float lsum = 0.f, lsq = 0.f;
  const int wid = blockIdx.x * 4 + w;
  const int nw  = gridDim.x * 4;
  for (int n = wid; n < N; n += nw) {
    const int r0 = rowptr[n], r1 = rowptr[n + 1];
    float s[8] = {0.f, 0.f, 0.f, 0.f, 0.f, 0.f, 0.f, 0.f};
    for (int j = r0 + g; j < r1; j += 8) {
      int a = csr_src[j];
      uint4 rv = *(const uint4*)&qb[(size_t)a * 64 + 8 * c];
      const __half2* hp = (const __half2*)&rv;
#pragma unroll
      for (int q = 0; q < 4; ++q) {
        float2 f2 = __half22float2(hp[q]);
        s[2 * q]     += f2.x;
        s[2 * q + 1] += f2.y;
      }
    }
    // butterfly over the g bits (lane bits 3,4,5)
#pragma unroll
    for (int m = 8; m < 64; m <<= 1)
#pragma unroll
      for (int q = 0; q < 8; ++q) s[q] += __shfl_xor(s[q], m);
    // lane (g,c) finalizes feature f = 8c + g
    float sv = s[0];
#pragma unroll
    for (int q = 1; q < 8; ++q) sv = (g == q) ? s[q] : sv;
    float cdeg = (float)(r1 - r0);
    cdeg = cdeg > 1.f ? cdeg : 1.f;
    const int f = 8 * c + g;
    float v = sv / cdeg + pb[(size_t)n * 64 + f];
    hpre[(size_t)n * 64 + f] = v;
    lsum += v;
    lsq  += v * v;
  }
  red[tid]       = lsum;
  red[256 + tid] = lsq;
  __syncthreads();
  if (tid < 64) {  // same lane->feature map in every wave
    float ts = red[tid] + red[tid + 64] + red[tid + 128] + red[tid + 192];
    float tq = red[256 + tid] + red[256 + tid + 64] + red[256 + tid + 128] + red[256 + tid + 192];
    int f = 8 * (tid & 7) + (tid >> 3);
    atomicAdd(&stats[f], ts);
    atomicAdd(&stats[64 + f], tq);
  }
}

// stats -> BN scale/shift: sc=g*invstd, sh=be-mean*sc
__global__ void k_finalize(float* stats, const float* __restrict__ g,
                           const float* __restrict__ be, int N) {
  int f = threadIdx.x;  // 64 threads
  float inv_n = 1.0f / (float)N;
  float mean = stats[f] * inv_n;
  float var  = stats[64 + f] * inv_n - mean * mean;
  float s = g[f] * rsqrtf(var + EPS);
  stats[128 + f] = s;
  stats[192 + f] = be[f] - mean * s;
}

// ---------------------------------------------------------------------------
// Fused edge MLP over (dseg, sbucket)-tiled edge order, MFMA layer 2.
// ---------------------------------------------------------------------------
__global__ __launch_bounds__(256, 4) void k_edge(
    const __half* __restrict__ U16, const float* __restrict__ V32,
    const float* __restrict__ attr,
    const int* __restrict__ csrc, const int* __restrict__ cdst,
    const int* __restrict__ ceid,
    const __half* __restrict__ W2Bws, const float* __restrict__ BTws,
    const float* __restrict__ bm2, const float* __restrict__ Wm3,
    const float* __restrict__ bm3, float* __restrict__ out2, int E) {
  __shared__ __align__(16) _Float16 Z1f[64 * 136];
  __shared__ __align__(16) _Float16 W2B[8192];
  __shared__ __align__(16) float attrL[64 * 16];
  __shared__ int idxL[128];
  __shared__ int eidL[64];

  const int tid  = threadIdx.x;
  const int c4   = tid & 31;
  const int lane = tid & 63;
  const int w    = tid >> 6;
  const int ln15 = lane & 15;
  const int quad = lane >> 4;

  for (int i = tid; i < 1024; i += 256)
    ((uint4*)W2B)[i] = ((const uint4*)W2Bws)[i];

  float bmv[4], w30[4], w31[4];
#pragma unroll
  for (int t = 0; t < 4; ++t) {
    bmv[t] = bm2[16 * t + ln15];
    w30[t] = Wm3[16 * t + ln15];
    w31[t] = Wm3[64 + 16 * t + ln15];
  }
  const float bm30 = bm3[0], bm31 = bm3[1];

  const __half2* uh2 = (const __half2*)U16;
  const float4*  v4  = (const float4*)V32;
  const float4*  at4 = (const float4*)attr;
  const float4*  bt4 = (const float4*)BTws;

  const int nt = (E + 63) >> 6;
  for (int t = blockIdx.x; t < nt; t += gridDim.x) {
    const int e0 = t << 6;
    __syncthreads();

    if (tid < 64) {
      int j = e0 + tid;
      idxL[tid]      = (j < E) ? csrc[j] : 0;
      idxL[64 + tid] = (j < E) ? cdst[j] : 0;
      eidL[tid]      = (j < E) ? ceid[j] : -1;
    }
    float4 breg[16];
#pragma unroll
    for (int k = 0; k < 16; ++k) breg[k] = bt4[k * 32 + c4];
    __syncthreads();

    {
      int e = tid >> 2, k4 = tid & 3;
      int eid = eidL[e];
      float4 av = make_float4(0.f, 0.f, 0.f, 0.f);
      if (eid >= 0) av = at4[(size_t)eid * 4 + k4];
      ((float4*)attrL)[tid] = av;
    }
    __syncthreads();

#pragma unroll
    for (int it = 0; it < 8; ++it) {
      const int e = it * 8 + (tid >> 5);
      uint2 ur = *(const uint2*)&uh2[(size_t)idxL[e] * 64 + 2 * c4];
      float2 u01 = __half22float2(*reinterpret_cast<__half2*>(&ur.x));
      float2 u23 = __half22float2(*reinterpret_cast<__half2*>(&ur.y));
      float4 b = v4[(size_t)idxL[64 + e] * 32 + c4];
      float sx = u01.x + b.x, sy = u01.y + b.y;
      float sz = u23.x + b.z, sw = u23.y + b.w;
#pragma unroll
      for (int k = 0; k < 16; ++k) {
        float av = attrL[e * 16 + k];
        sx += av * breg[k].x; sy += av * breg[k].y;
        sz += av * breg[k].z; sw += av * breg[k].w;
      }
      __half2* zp = (__half2*)&Z1f[e * 136 + 4 * c4];
      zp[0] = __floats2half2_rn(fmaxf(sx, 0.f), fmaxf(sy, 0.f));
      zp[1] = __floats2half2_rn(fmaxf(sz, 0.f), fmaxf(sw, 0.f));
    }
    __syncthreads();

    f32x4 acc[4];
#pragma unroll
    for (int tt = 0; tt < 4; ++tt)
      acc[tt] = (f32x4){bmv[tt], bmv[tt], bmv[tt], bmv[tt]};
#pragma unroll
    for (int kc = 0; kc < 4; ++kc) {
      h8 a = *(const h8*)&Z1f[(16 * w + ln15) * 136 + 32 * kc + 8 * quad];
#pragma unroll
      for (int tt = 0; tt < 4; ++tt) {
        h8 bf = *(const h8*)&W2B[((kc * 4 + tt) * 64 + lane) * 8];
        acc[tt] = __builtin_amdgcn_mfma_f32_16x16x32_f16(a, bf, acc[tt], 0, 0, 0);
      }
    }

    float p0[4], p1[4];
#pragma unroll
    for (int r = 0; r < 4; ++r) { p0[r] = 0.f; p1[r] = 0.f; }
#pragma unroll
    for (int tt = 0; tt < 4; ++tt)
#pragma unroll
      for (int r = 0; r < 4; ++r) {
        float z = fmaxf(acc[tt][r], 0.f);
        p0[r] += z * w30[tt];
        p1[r] += z * w31[tt];
      }
#pragma unroll
    for (int r = 0; r < 4; ++r) {
#pragma unroll
      for (int m = 1; m < 16; m <<= 1) {
        p0[r] += __shfl_xor(p0[r], m);
        p1[r] += __shfl_xor(p1[r], m);
      }
      if (ln15 == 0) {
        int e = 16 * w + 4 * quad + r;
        int j = e0 + e;
        if (j < E)
          *(float2*)&out2[(size_t)j * 2] = make_float2(p0[r] + bm30, p1[r] + bm31);
      }
    }
  }
}

extern "C" void kernel_launch(void* const* d_in, const int* in_sizes, int n_in,
                              void* d_out, int out_size, void* d_ws, size_t ws_size,
                              hipStream_t stream) {
  const float* x    = (const float*)d_in[0];
  const int*   ei   = (const int*)d_in[1];
  const float* attr = (const float*)d_in[2];
  const float* W1l  = (const float*)d_in[3];
  const float* b1l  = (const float*)d_in[4];
  const float* W1r  = (const float*)d_in[5];
  const float* g1   = (const float*)d_in[6];
  const float* be1  = (const float*)d_in[7];
  const float* W2l  = (const float*)d_in[8];
  const float* b2l  = (const float*)d_in[9];
  const float* W2r  = (const float*)d_in[10];
  const float* g2   = (const float*)d_in[11];
  const float* be2  = (const float*)d_in[12];
  const float* Wm1  = (const float*)d_in[13];
  const float* bm1  = (const float*)d_in[14];
  const float* Wm2  = (const float*)d_in[15];
  const float* bm2  = (const float*)d_in[16];
  const float* Wm3  = (const float*)d_in[17];
  const float* bm3  = (const float*)d_in[18];
  float* out = (float*)d_out;

  const int N = in_sizes[0] / 128;
  const int E = in_sizes[1] / 2;
  const int* srcI = ei;
  const int* dstI = ei + E;

  float* ws = (float*)d_ws;
  const size_t NF = (size_t)N * 64;
  float*  P32 = ws;                        // [N][64] f32
  float*  H1  = ws + NF;                   // [N][64] f32 (reused as H2)
  float*  V32 = ws + 2 * NF;               // [N][128] f32
  __half* Q16 = (__half*)(ws + 4 * NF);    // [N][64] f16
  __half* U16 = (__half*)(ws + 4 * NF + NF / 2);  // [N][128] f16
  float* small  = ws + 5 * NF + NF / 2;
  float* stats1 = small;          // 256
  float* stats2 = stats1 + 256;   // 256
  float* Wt1    = stats2 + 256;   // 128*128
  float* Wt2    = Wt1 + 16384;    // 64*128
  float* Wt3    = Wt2 + 8192;     // 64*256
  float* bias1  = Wt3 + 16384;    // 128
  float* bias2  = bias1 + 128;    // 128
  float* bias3  = bias2 + 128;    // 256
  float* BTws   = bias3 + 256;    // 16*128
  __half* W2B   = (__half*)(BTws + 2048);   // 8192 halfs = 4096 floats
  int* rowptr = (int*)(BTws + 2048 + 4096); // N+1
  int* cursor = rowptr + (N + 1);           // N
  int* deg    = cursor + N;                 // N
  int* csrsrc = deg + N;                    // E
  int* csrdst = csrsrc + E;                 // E
  int* csreid = csrdst + E;                 // E
  int* hist   = csreid + E;                 // NBLK*nb  (<= 256*1024)
  // poff/base follow hist; sized at runtime below.

  // 2D-tiled edge-order buffers alias dead regions (used only after k_gemm<64,3>):
  int* s2  = (int*)P32;         // E  (P32 dead after 2nd k_agg)
  int* d2  = s2 + E;            // E
  int* e2  = d2 + E;            // E
  int* pos = e2 + E;            // E   (4E ints == NF floats exactly for deg 16)
  float* out2 = H1;             // 2E floats (H1 dead after k_gemm<64,3>)

  const int nseg = (N + 4095) >> 12;   // 4096-node segments (13 for N=50000)
  const int nb   = nseg * nseg;        // 169 buckets
  const int chunk = (E + NBLK - 1) / NBLK;
  int* poff = hist + (size_t)NBLK * nb;
  int* base = poff + (size_t)NBLK * nb;

  hipMemsetAsync(deg, 0, (size_t)N * sizeof(int), stream);
  hipMemsetAsync(stats1, 0, 512 * sizeof(float), stream);

  // ---- weight prep + degree histogram (one launch) ----
  const int eBlocks = (E + 255) / 256;
  const int prepBlocks = (51712 + 255) / 256;
  k_prep_hist<<<prepBlocks + eBlocks, 256, 0, stream>>>(
      W1l, W1r, b1l, W2l, W2r, b2l, Wm1, bm1, Wm2,
      Wt1, Wt2, Wt3, bias1, bias2, bias3, BTws, W2B,
      dstI, deg, E, prepBlocks);
  k_scan<<<1, 1024, 0, stream>>>(deg, rowptr, cursor, N);
  k_fill<<<eBlocks, 256, 0, stream>>>(srcI, dstI, cursor, csrsrc, csrdst,
                                      csreid, E);

  // ---- tiled-order histogram + scan (contention-free, off critical buffers) ----
  k_hist<<<NBLK, 256, 0, stream>>>(csrsrc, csrdst, hist, E, nseg, nb, chunk);
  k_scan2b<<<1, 1024, 0, stream>>>(hist, poff, base, nb);

  const int mTiles = (N + 63) / 64;

  // ---- conv1: Q16 = fp16(x@W1l^T), P32 = x@W1r^T + b1l ----
  k_gemm<128, 0><<<mTiles, 256, 0, stream>>>(x, nullptr, Wt1, bias1, Q16, P32, N, 128);
  k_agg<<<1024, 256, 0, stream>>>(Q16, P32, rowptr, csrsrc, H1, stats1, N);
  k_finalize<<<1, 64, 0, stream>>>(stats1, g1, be1, N);

  // ---- conv2 (BN1+relu fused into GEMM input) ----
  k_gemm<64, 0><<<mTiles, 256, 0, stream>>>(H1, stats1, Wt2, bias2, Q16, P32, N, 128);
  k_agg<<<1024, 256, 0, stream>>>(Q16, P32, rowptr, csrsrc, H1, stats2, N);  // H2=H1
  k_finalize<<<1, 64, 0, stream>>>(stats2, g2, be2, N);

  // ---- U16 / V32 in one launch (BN2+relu fused) ----
  k_gemm<64, 3><<<dim3(mTiles, 2), 256, 0, stream>>>(H1, stats2, Wt3, bias3,
                                                     U16, V32, N, 256);

  // ---- scatter into 2D-tiled order (P32/H1 now dead -> buffers valid) ----
  k_fill2b<<<NBLK, 256, 0, stream>>>(csrsrc, csrdst, csreid, poff, base,
                                     s2, d2, e2, pos, E, nseg, nb, chunk);

  // ---- fused edge MLP over tiled edges (MFMA layer 2), coalesced out2 ----
  k_edge<<<1024, 256, 0, stream>>>(U16, V32, attr, s2, d2, e2,
                                   W2B, BTws, bm2, Wm3, bm3, out2, E);
  // ---- inverse-permute to final output order ----
  k_scatter_out<<<eBlocks, 256, 0, stream>>>(out2, pos, out, E);
}

// Round 3
// 583.905 us; speedup vs baseline: 4.3567x; 1.2040x over previous
//
#include <hip/hip_runtime.h>
#include <hip/hip_fp16.h>

// ---------------------------------------------------------------------------
// EdgeClassifierGNN: 2x SAGEConv(mean)+BN+ReLU, then 3-layer edge MLP.
// Trick 1: lin_l before mean-aggregation (64-wide gather).
// Trick 3: CSR by dst -> atomic-free aggregation; k_edge in dst order.
// Trick 4: node linears via register-blocked GEMM, BN fused on input.
// Trick 6: k_edge layer 2 via v_mfma_f32_16x16x32_f16 + shfl epilogue.
// Trick 7 (r9): k_agg wave-per-node with 8-edges-per-load gather + butterfly.
// Trick 10 (r12): k_edge layer 1 ALSO via MFMA, gathering the 64-dim fp16
//          node features h2 directly (one 6.4 MB table, 128 B/edge instead
//          of 256 B/edge from 38 MB of U/V tables). A-fragments are built
//          straight from the gather loads (quad q holds k-halves q*8..q*8+7
//          of row ln15 == the 16x16x32 A layout), so no staging LDS and no
//          __syncthreads in the main loop (each wave owns its 16 Z1 rows).
//          K = 160 = [h_src(64) | h_dst(64) | attr(16) | pad(16)].
//          out written coalesced in CSR order then inverse-permuted (pos
//          recorded by k_fill). 2D-tiling machinery of r10/r11 removed.
// ---------------------------------------------------------------------------

#define EPS 1e-5f

typedef _Float16 h8 __attribute__((ext_vector_type(8)));
typedef float f32x4 __attribute__((ext_vector_type(4)));

// ---------------- CSR build + weight prep (merged) ----------------
// prep elements: Wt1 16384 | Wt2 8192 | bias1 128 | bias2 128 | W2B 8192 |
//                W1B 20480  => 53504 total
__global__ __launch_bounds__(256) void k_prep_hist(
    const float* __restrict__ W1l, const float* __restrict__ W1r,
    const float* __restrict__ b1l,
    const float* __restrict__ W2l, const float* __restrict__ W2r,
    const float* __restrict__ b2l,
    const float* __restrict__ Wm1, const float* __restrict__ Wm2,
    float* __restrict__ Wt1, float* __restrict__ Wt2,
    float* __restrict__ bias1, float* __restrict__ bias2,
    __half* __restrict__ W2B, __half* __restrict__ W1B,
    const int* __restrict__ dst, int* __restrict__ deg, int E, int prepBlocks) {
  if ((int)blockIdx.x >= prepBlocks) {
    int e = (blockIdx.x - prepBlocks) * 256 + threadIdx.x;
    if (e < E) atomicAdd(&deg[dst[e]], 1);
    return;
  }
  int idx = blockIdx.x * 256 + threadIdx.x;
  if (idx < 16384) {  // Wt1 [128k x 128f] = [W1l | W1r]^T
    int k = idx >> 7, f = idx & 127;
    Wt1[idx] = (f < 64) ? W1l[f * 128 + k] : W1r[(f - 64) * 128 + k];
    return;
  }
  idx -= 16384;
  if (idx < 8192) {   // Wt2 [64k x 128f] = [W2l | W2r]^T
    int k = idx >> 7, f = idx & 127;
    Wt2[idx] = (f < 64) ? W2l[f * 64 + k] : W2r[(f - 64) * 64 + k];
    return;
  }
  idx -= 8192;
  if (idx < 128) { bias1[idx] = (idx < 64) ? 0.f : b1l[idx - 64]; return; }
  idx -= 128;
  if (idx < 128) { bias2[idx] = (idx < 64) ? 0.f : b2l[idx - 64]; return; }
  idx -= 128;
  if (idx < 8192) {   // W2B: Wm2^T pre-swizzled to MFMA B-fragment layout
    int j = idx & 7, l = (idx >> 3) & 63, f = idx >> 9;
    int kc = f >> 2, tt = f & 3;
    int col = 16 * tt + (l & 15);
    int k = 32 * kc + (l >> 4) * 8 + j;
    W2B[idx] = __float2half(Wm2[col * 128 + k]);
    return;
  }
  idx -= 8192;
  if (idx < 20480) {  // W1B: layer-1 Wcat (160x128) in MFMA B-fragment layout
    int j = idx & 7, l = (idx >> 3) & 63, f = idx >> 9;  // f = kc*8+nc, 0..39
    int kc = f >> 3, nc = f & 7;
    int k = 32 * kc + (l >> 4) * 8 + j;   // 0..159
    int n = 16 * nc + (l & 15);           // 0..127
    float w;
    if (k < 64)       w = Wm1[n * 144 + k];            // src cols 0..63
    else if (k < 128) w = Wm1[n * 144 + 80 + (k - 64)];// dst cols 80..143
    else if (k < 144) w = Wm1[n * 144 + 64 + (k - 128)];// attr cols 64..79
    else              w = 0.f;                          // pad
    W1B[idx] = __float2half(w);
    return;
  }
}

__global__ __launch_bounds__(1024) void k_scan(
    const int* __restrict__ deg, int* __restrict__ rowptr,
    int* __restrict__ cursor, int N) {
  __shared__ int wsum[16];
  __shared__ int carry;
  const int lane = threadIdx.x & 63;
  const int w    = threadIdx.x >> 6;
  if (threadIdx.x == 0) carry = 0;
  __syncthreads();
  for (int base = 0; base < N; base += 1024) {
    int i = base + threadIdx.x;
    int v = (i < N) ? deg[i] : 0;
    int incl = v;
#pragma unroll
    for (int off = 1; off < 64; off <<= 1) {
      int t = __shfl_up(incl, off);
      if (lane >= off) incl += t;
    }
    if (lane == 63) wsum[w] = incl;
    __syncthreads();
    if (w == 0) {
      int ws_ = (lane < 16) ? wsum[lane] : 0;
      int wincl = ws_;
#pragma unroll
      for (int off = 1; off < 16; off <<= 1) {
        int t = __shfl_up(wincl, off);
        if (lane >= off) wincl += t;
      }
      if (lane < 16) wsum[lane] = wincl;
    }
    __syncthreads();
    int woff = carry + (w > 0 ? wsum[w - 1] : 0);
    int excl = woff + incl - v;
    if (i < N) { rowptr[i] = excl; cursor[i] = excl; }
    int tot = wsum[15];
    __syncthreads();
    if (threadIdx.x == 0) carry += tot;
    __syncthreads();
  }
  if (threadIdx.x == 0) rowptr[N] = carry;
}

// CSR scatter; also records inverse permutation pos[eid] = CSR slot.
__global__ __launch_bounds__(256) void k_fill(
    const int* __restrict__ src, const int* __restrict__ dst,
    int* __restrict__ cursor, int* __restrict__ csr_src,
    int* __restrict__ csr_dst, int* __restrict__ csr_eid,
    int* __restrict__ pos, int E) {
  int e = blockIdx.x * 256 + threadIdx.x;
  if (e < E) {
    int d = dst[e];
    int p = atomicAdd(&cursor[d], 1);
    csr_src[p] = src[e];
    csr_dst[p] = d;
    csr_eid[p] = e;
    pos[e] = p;
  }
}

// final inverse-permute: coalesced write of out, gather from L2-resident out2
__global__ __launch_bounds__(256) void k_scatter_out(
    const float* __restrict__ out2, const int* __restrict__ pos,
    float* __restrict__ out, int E) {
  int e = blockIdx.x * 256 + threadIdx.x;
  if (e < E) {
    int p = pos[e];
    *(float2*)&out[(size_t)e * 2] = *(const float2*)&out2[(size_t)p * 2];
  }
}

// ---------------- register-blocked node GEMM ----------------
// MODE 0: cols 0-63 -> half outH (stride 64), 64-127 -> float outF (stride 64)
template<int K, int MODE>
__global__ __launch_bounds__(256) void k_gemm(
    const float* __restrict__ X, const float* __restrict__ stats,
    const float* __restrict__ Wt, const float* __restrict__ bias,
    __half* __restrict__ outH, float* __restrict__ outF, int N, int Ftot) {
  __shared__ __align__(16) float Xs[32][68];
  __shared__ __align__(16) float Ws_[32][128];
  const int tid = threadIdx.x;
  const int tx  = tid & 15;
  const int ty  = tid >> 4;
  const int n0  = blockIdx.x * 64;
  float acc[4][8];
#pragma unroll
  for (int j = 0; j < 8; ++j) {
    float bv = bias[8 * tx + j];
#pragma unroll
    for (int i = 0; i < 4; ++i) acc[i][j] = bv;
  }
  for (int k0 = 0; k0 < K; k0 += 32) {
    __syncthreads();
#pragma unroll
    for (int l = 0; l < 2; ++l) {
      int idx = tid * 2 + l;
      int kq = idx & 7, n = idx >> 3;
      float4 xv = make_float4(0.f, 0.f, 0.f, 0.f);
      if (n0 + n < N) xv = *(const float4*)&X[(size_t)(n0 + n) * K + k0 + kq * 4];
      if (stats) {
        int kb = k0 + kq * 4;
        xv.x = fmaxf(xv.x * stats[128 + kb + 0] + stats[192 + kb + 0], 0.f);
        xv.y = fmaxf(xv.y * stats[128 + kb + 1] + stats[192 + kb + 1], 0.f);
        xv.z = fmaxf(xv.z * stats[128 + kb + 2] + stats[192 + kb + 2], 0.f);
        xv.w = fmaxf(xv.w * stats[128 + kb + 3] + stats[192 + kb + 3], 0.f);
      }
      Xs[kq * 4 + 0][n] = xv.x;
      Xs[kq * 4 + 1][n] = xv.y;
      Xs[kq * 4 + 2][n] = xv.z;
      Xs[kq * 4 + 3][n] = xv.w;
    }
#pragma unroll
    for (int l = 0; l < 4; ++l) {
      int idx = tid + l * 256;
      int kr = idx >> 5, fc = idx & 31;
      *(float4*)&Ws_[kr][fc * 4] =
          *(const float4*)&Wt[(size_t)(k0 + kr) * Ftot + fc * 4];
    }
    __syncthreads();
#pragma unroll
    for (int kk = 0; kk < 32; ++kk) {
      float4 a  = *(const float4*)&Xs[kk][4 * ty];
      float4 b0 = *(const float4*)&Ws_[kk][8 * tx];
      float4 b1 = *(const float4*)&Ws_[kk][8 * tx + 4];
      float aa[4] = {a.x, a.y, a.z, a.w};
      float bb[8] = {b0.x, b0.y, b0.z, b0.w, b1.x, b1.y, b1.z, b1.w};
#pragma unroll
      for (int i = 0; i < 4; ++i)
#pragma unroll
        for (int j = 0; j < 8; ++j) acc[i][j] += aa[i] * bb[j];
    }
  }
#pragma unroll
  for (int i = 0; i < 4; ++i) {
    int n = n0 + 4 * ty + i;
    if (n >= N) continue;
    if (tx < 8) {
      __half2 hh[4];
#pragma unroll
      for (int c = 0; c < 4; ++c)
        hh[c] = __floats2half2_rn(acc[i][2 * c], acc[i][2 * c + 1]);
      *(uint4*)&outH[(size_t)n * 64 + 8 * tx] = *(uint4*)hh;
    } else {
      float* cp = outF + (size_t)n * 64 + 8 * tx - 64;
      *(float4*)cp = make_float4(acc[i][0], acc[i][1], acc[i][2], acc[i][3]);
      *(float4*)(cp + 4) = make_float4(acc[i][4], acc[i][5], acc[i][6], acc[i][7]);
    }
  }
}

// ---------------- fused aggregate + mean + residual + BN stats ----------------
__global__ __launch_bounds__(256) void k_agg(
    const __half* __restrict__ qb, const float* __restrict__ pb,
    const int* __restrict__ rowptr, const int* __restrict__ csr_src,
    float* __restrict__ hpre, float* __restrict__ stats, int N) {
  __shared__ float red[512];
  const int tid  = threadIdx.x;
  const int w    = tid >> 6;
  const int lane = tid & 63;
  const int g    = lane >> 3, c = lane & 7;
  float lsum = 0.f, lsq = 0.f;
  const int wid = blockIdx.x * 4 + w;
  const int nw  = gridDim.x * 4;
  for (int n = wid; n < N; n += nw) {
    const int r0 = rowptr[n], r1 = rowptr[n + 1];
    float s[8] = {0.f, 0.f, 0.f, 0.f, 0.f, 0.f, 0.f, 0.f};
    for (int j = r0 + g; j < r1; j += 8) {
      int a = csr_src[j];
      uint4 rv = *(const uint4*)&qb[(size_t)a * 64 + 8 * c];
      const __half2* hp = (const __half2*)&rv;
#pragma unroll
      for (int q = 0; q < 4; ++q) {
        float2 f2 = __half22float2(hp[q]);
        s[2 * q]     += f2.x;
        s[2 * q + 1] += f2.y;
      }
    }
#pragma unroll
    for (int m = 8; m < 64; m <<= 1)
#pragma unroll
      for (int q = 0; q < 8; ++q) s[q] += __shfl_xor(s[q], m);
    float sv = s[0];
#pragma unroll
    for (int q = 1; q < 8; ++q) sv = (g == q) ? s[q] : sv;
    float cdeg = (float)(r1 - r0);
    cdeg = cdeg > 1.f ? cdeg : 1.f;
    const int f = 8 * c + g;
    float v = sv / cdeg + pb[(size_t)n * 64 + f];
    hpre[(size_t)n * 64 + f] = v;
    lsum += v;
    lsq  += v * v;
  }
  red[tid]       = lsum;
  red[256 + tid] = lsq;
  __syncthreads();
  if (tid < 64) {
    float ts = red[tid] + red[tid + 64] + red[tid + 128] + red[tid + 192];
    float tq = red[256 + tid] + red[256 + tid + 64] + red[256 + tid + 128] + red[256 + tid + 192];
    int f = 8 * (tid & 7) + (tid >> 3);
    atomicAdd(&stats[f], ts);
    atomicAdd(&stats[64 + f], tq);
  }
}

// stats -> BN scale/shift: sc=g*invstd, sh=be-mean*sc
__global__ void k_finalize(float* stats, const float* __restrict__ g,
                           const float* __restrict__ be, int N) {
  int f = threadIdx.x;  // 64 threads
  float inv_n = 1.0f / (float)N;
  float mean = stats[f] * inv_n;
  float var  = stats[64 + f] * inv_n - mean * mean;
  float s = g[f] * rsqrtf(var + EPS);
  stats[128 + f] = s;
  stats[192 + f] = be[f] - mean * s;
}

// BN2+relu -> fp16 node features h2 (the single 6.4 MB gather table)
__global__ __launch_bounds__(256) void k_bn(
    const float* __restrict__ H1, const float* __restrict__ stats,
    __half* __restrict__ H2, int N) {
  int idx = blockIdx.x * 256 + threadIdx.x;
  if (idx >= N * 8) return;
  int n = idx >> 3, f8 = (idx & 7) * 8;
  float4 h0 = *(const float4*)&H1[(size_t)n * 64 + f8];
  float4 h1 = *(const float4*)&H1[(size_t)n * 64 + f8 + 4];
  const float* sc = stats + 128 + f8;
  const float* sh = stats + 192 + f8;
  __half2 hh[4];
  hh[0] = __floats2half2_rn(fmaxf(h0.x * sc[0] + sh[0], 0.f),
                            fmaxf(h0.y * sc[1] + sh[1], 0.f));
  hh[1] = __floats2half2_rn(fmaxf(h0.z * sc[2] + sh[2], 0.f),
                            fmaxf(h0.w * sc[3] + sh[3], 0.f));
  hh[2] = __floats2half2_rn(fmaxf(h1.x * sc[4] + sh[4], 0.f),
                            fmaxf(h1.y * sc[5] + sh[5], 0.f));
  hh[3] = __floats2half2_rn(fmaxf(h1.z * sc[6] + sh[6], 0.f),
                            fmaxf(h1.w * sc[7] + sh[7], 0.f));
  *(uint4*)&H2[(size_t)n * 64 + f8] = *(uint4*)hh;
}

// ---------------------------------------------------------------------------
// Fused edge MLP, all-MFMA: layer1 (K=160) + layer2 + shfl layer3.
// No per-tile __syncthreads: each wave owns its 16 rows of Z1f.
// ---------------------------------------------------------------------------
__global__ __launch_bounds__(256, 2) void k_edge(
    const __half* __restrict__ H2, const float* __restrict__ attr,
    const int* __restrict__ csrc, const int* __restrict__ cdst,
    const int* __restrict__ ceid,
    const __half* __restrict__ W1Bws, const __half* __restrict__ W2Bws,
    const float* __restrict__ bm1, const float* __restrict__ bm2,
    const float* __restrict__ Wm3, const float* __restrict__ bm3,
    float* __restrict__ out2, int E) {
  __shared__ __align__(16) _Float16 W1B[20480];
  __shared__ __align__(16) _Float16 W2B[8192];
  __shared__ __align__(16) _Float16 Z1f[64 * 136];

  const int tid  = threadIdx.x;
  const int lane = tid & 63;
  const int w    = tid >> 6;
  const int ln15 = lane & 15;
  const int quad = lane >> 4;

  for (int i = tid; i < 2560; i += 256)
    ((uint4*)W1B)[i] = ((const uint4*)W1Bws)[i];
  for (int i = tid; i < 1024; i += 256)
    ((uint4*)W2B)[i] = ((const uint4*)W2Bws)[i];

  float bm1v[8];
#pragma unroll
  for (int nc = 0; nc < 8; ++nc) bm1v[nc] = bm1[16 * nc + ln15];
  float bmv[4], w30[4], w31[4];
#pragma unroll
  for (int t = 0; t < 4; ++t) {
    bmv[t] = bm2[16 * t + ln15];
    w30[t] = Wm3[16 * t + ln15];
    w31[t] = Wm3[64 + 16 * t + ln15];
  }
  const float bm30 = bm3[0], bm31 = bm3[1];
  __syncthreads();

  const int nt = (E + 63) >> 6;
  for (int t = blockIdx.x; t < nt; t += gridDim.x) {
    const int e0 = t << 6;
    int er = e0 + 16 * w + ln15;
    if (er >= E) er = E - 1;
    const int s   = csrc[er];
    const int d   = cdst[er];
    const int eid = ceid[er];

    // A-fragments straight from gathers: row = ln15, k-halves = quad*8..+7
    h8 af[5];
    af[0] = *(const h8*)&H2[(size_t)s * 64 + 8 * quad];
    af[1] = *(const h8*)&H2[(size_t)s * 64 + 32 + 8 * quad];
    af[2] = *(const h8*)&H2[(size_t)d * 64 + 8 * quad];
    af[3] = *(const h8*)&H2[(size_t)d * 64 + 32 + 8 * quad];
    {
      h8 a4 = {0, 0, 0, 0, 0, 0, 0, 0};
      if (quad < 2) {
        float4 f0 = *(const float4*)&attr[(size_t)eid * 16 + 8 * quad];
        float4 f1 = *(const float4*)&attr[(size_t)eid * 16 + 8 * quad + 4];
        a4[0] = (_Float16)f0.x; a4[1] = (_Float16)f0.y;
        a4[2] = (_Float16)f0.z; a4[3] = (_Float16)f0.w;
        a4[4] = (_Float16)f1.x; a4[5] = (_Float16)f1.y;
        a4[6] = (_Float16)f1.z; a4[7] = (_Float16)f1.w;
      }
      af[4] = a4;
    }

    // ---- layer 1: z1[16e x 128f] = A(16x160) x Wcat(160x128) + bm1 ----
    f32x4 acc1[8];
#pragma unroll
    for (int nc = 0; nc < 8; ++nc)
      acc1[nc] = (f32x4){bm1v[nc], bm1v[nc], bm1v[nc], bm1v[nc]};
#pragma unroll
    for (int kc = 0; kc < 5; ++kc)
#pragma unroll
      for (int nc = 0; nc < 8; ++nc) {
        h8 bf = *(const h8*)&W1B[((kc * 8 + nc) << 9) + (lane << 3)];
        acc1[nc] = __builtin_amdgcn_mfma_f32_16x16x32_f16(af[kc], bf, acc1[nc], 0, 0, 0);
      }

    // relu -> fp16 -> Z1 (C-layout: row = quad*4+r, col = 16*nc+ln15)
    const int ebase = 16 * w + 4 * quad;
#pragma unroll
    for (int nc = 0; nc < 8; ++nc)
#pragma unroll
      for (int r = 0; r < 4; ++r)
        Z1f[(ebase + r) * 136 + 16 * nc + ln15] =
            (_Float16)fmaxf(acc1[nc][r], 0.f);

    // ---- layer 2 (wave-local rows; no cross-wave sync needed) ----
    f32x4 acc2[4];
#pragma unroll
    for (int tt = 0; tt < 4; ++tt)
      acc2[tt] = (f32x4){bmv[tt], bmv[tt], bmv[tt], bmv[tt]};
#pragma unroll
    for (int kc = 0; kc < 4; ++kc) {
      h8 a = *(const h8*)&Z1f[(16 * w + ln15) * 136 + 32 * kc + 8 * quad];
#pragma unroll
      for (int tt = 0; tt < 4; ++tt) {
        h8 bf = *(const h8*)&W2B[((kc * 4 + tt) * 64 + lane) * 8];
        acc2[tt] = __builtin_amdgcn_mfma_f32_16x16x32_f16(a, bf, acc2[tt], 0, 0, 0);
      }
    }

    // ---- layer 3 + output (coalesced, CSR order) ----
    float p0[4], p1[4];
#pragma unroll
    for (int r = 0; r < 4; ++r) { p0[r] = 0.f; p1[r] = 0.f; }
#pragma unroll
    for (int tt = 0; tt < 4; ++tt)
#pragma unroll
      for (int r = 0; r < 4; ++r) {
        float z = fmaxf(acc2[tt][r], 0.f);
        p0[r] += z * w30[tt];
        p1[r] += z * w31[tt];
      }
#pragma unroll
    for (int r = 0; r < 4; ++r) {
#pragma unroll
      for (int m = 1; m < 16; m <<= 1) {
        p0[r] += __shfl_xor(p0[r], m);
        p1[r] += __shfl_xor(p1[r], m);
      }
      if (ln15 == 0) {
        int j = e0 + 16 * w + 4 * quad + r;
        if (j < E)
          *(float2*)&out2[(size_t)j * 2] = make_float2(p0[r] + bm30, p1[r] + bm31);
      }
    }
  }
}

extern "C" void kernel_launch(void* const* d_in, const int* in_sizes, int n_in,
                              void* d_out, int out_size, void* d_ws, size_t ws_size,
                              hipStream_t stream) {
  const float* x    = (const float*)d_in[0];
  const int*   ei   = (const int*)d_in[1];
  const float* attr = (const float*)d_in[2];
  const float* W1l  = (const float*)d_in[3];
  const float* b1l  = (const float*)d_in[4];
  const float* W1r  = (const float*)d_in[5];
  const float* g1   = (const float*)d_in[6];
  const float* be1  = (const float*)d_in[7];
  const float* W2l  = (const float*)d_in[8];
  const float* b2l  = (const float*)d_in[9];
  const float* W2r  = (const float*)d_in[10];
  const float* g2   = (const float*)d_in[11];
  const float* be2  = (const float*)d_in[12];
  const float* Wm1  = (const float*)d_in[13];
  const float* bm1  = (const float*)d_in[14];
  const float* Wm2  = (const float*)d_in[15];
  const float* bm2  = (const float*)d_in[16];
  const float* Wm3  = (const float*)d_in[17];
  const float* bm3  = (const float*)d_in[18];
  float* out = (float*)d_out;

  const int N = in_sizes[0] / 128;
  const int E = in_sizes[1] / 2;
  const int* srcI = ei;
  const int* dstI = ei + E;

  float* ws = (float*)d_ws;
  const size_t NF = (size_t)N * 64;
  float*  P32 = ws;                        // [N][64] f32
  float*  H1  = ws + NF;                   // [N][64] f32 (reused as H2pre)
  __half* Q16 = (__half*)(ws + 2 * NF);    // [N][64] f16 (later: H2 table)
  float* small  = ws + 2 * NF + NF / 2;
  float* stats1 = small;          // 256
  float* stats2 = stats1 + 256;   // 256
  float* Wt1    = stats2 + 256;   // 128*128
  float* Wt2    = Wt1 + 16384;    // 64*128
  float* bias1  = Wt2 + 8192;     // 128
  float* bias2  = bias1 + 128;    // 128
  __half* W1B   = (__half*)(bias2 + 128);            // 20480 halves = 10240 f
  __half* W2B   = (__half*)(bias2 + 128 + 10240);    // 8192 halves = 4096 f
  int* rowptr = (int*)(bias2 + 128 + 10240 + 4096);  // N+1
  int* cursor = rowptr + (N + 1);           // N
  int* deg    = cursor + N;                 // N
  int* csrsrc = deg + N;                    // E
  int* csrdst = csrsrc + E;                 // E
  int* csreid = csrdst + E;                 // E
  int* pos    = csreid + E;                 // E

  __half* H2  = Q16;   // Q16 dead after 2nd k_agg; k_bn writes H2 there
  float* out2 = H1;    // H1 dead after k_bn reads it

  hipMemsetAsync(deg, 0, (size_t)N * sizeof(int), stream);
  hipMemsetAsync(stats1, 0, 512 * sizeof(float), stream);

  // ---- weight prep + degree histogram (one launch) ----
  const int eBlocks = (E + 255) / 256;
  const int prepBlocks = (53504 + 255) / 256;
  k_prep_hist<<<prepBlocks + eBlocks, 256, 0, stream>>>(
      W1l, W1r, b1l, W2l, W2r, b2l, Wm1, Wm2,
      Wt1, Wt2, bias1, bias2, W2B, W1B,
      dstI, deg, E, prepBlocks);
  k_scan<<<1, 1024, 0, stream>>>(deg, rowptr, cursor, N);
  k_fill<<<eBlocks, 256, 0, stream>>>(srcI, dstI, cursor, csrsrc, csrdst,
                                      csreid, pos, E);

  const int mTiles = (N + 63) / 64;

  // ---- conv1: Q16 = fp16(x@W1l^T), P32 = x@W1r^T + b1l ----
  k_gemm<128, 0><<<mTiles, 256, 0, stream>>>(x, nullptr, Wt1, bias1, Q16, P32, N, 128);
  k_agg<<<1024, 256, 0, stream>>>(Q16, P32, rowptr, csrsrc, H1, stats1, N);
  k_finalize<<<1, 64, 0, stream>>>(stats1, g1, be1, N);

  // ---- conv2 (BN1+relu fused into GEMM input) ----
  k_gemm<64, 0><<<mTiles, 256, 0, stream>>>(H1, stats1, Wt2, bias2, Q16, P32, N, 128);
  k_agg<<<1024, 256, 0, stream>>>(Q16, P32, rowptr, csrsrc, H1, stats2, N);  // H2pre=H1
  k_finalize<<<1, 64, 0, stream>>>(stats2, g2, be2, N);

  // ---- BN2+relu -> fp16 h2 table (overwrites Q16 region) ----
  k_bn<<<(N * 8 + 255) / 256, 256, 0, stream>>>(H1, stats2, H2, N);

  // ---- fused all-MFMA edge MLP over dst-CSR edges, coalesced out2 ----
  k_edge<<<1024, 256, 0, stream>>>(H2, attr, csrsrc, csrdst, csreid,
                                   W1B, W2B, bm1, bm2, Wm3, bm3, out2, E);
  // ---- inverse-permute to final output order ----
  k_scatter_out<<<eBlocks, 256, 0, stream>>>(out2, pos, out, E);
}